// Round 1
// baseline (570.185 us; speedup 1.0000x reference)
//
#include <hip/hip_runtime.h>
#include <math.h>

constexpr int In = 128, Rn = 36, Rp = 40, Cn = 64, Ln = 32, Dn = 512;
constexpr int CH = 128, NCH = 4, IST = 132, CST = 132;
constexpr float EPSf = 1e-8f, LLSE = 6.0f, LSM = 9.0f, SLOPE = 0.1f;

__device__ __forceinline__ float dot4(float4 a, float4 b) {
  return a.x * b.x + a.y * b.y + a.z * b.z + a.w * b.w;
}

extern "C" __global__ __launch_bounds__(256, 2)
void scan_t2i(const float* __restrict__ images, const float* __restrict__ captions,
              const int* __restrict__ cap_lens, float* __restrict__ out)
{
  __shared__ float simg[Rp * IST];      // 21120 B
  __shared__ float scap[Ln * CST];      // 16896 B
  __shared__ float spart[4 * Rp * Ln];  // 20480 B
  __shared__ float sS[Rp * Ln];         // 5120 B
  __shared__ float srown[Rn];
  __shared__ float srs[Ln];

  const int tid = threadIdx.x;
  const int blk = blockIdx.x;
  const int c = blk & (Cn - 1);
  const int i = blk >> 6;
  const int len = cap_lens[c];

  const float* gimg = images + (size_t)i * Rn * Dn;
  const float* gcap = captions + (size_t)c * Ln * Dn;

  auto stage = [&](int ch) {
    const int base = ch * CH;
    #pragma unroll
    for (int t = 0; t < 5; ++t) {           // 40 rows * 32 float4
      int idx = tid + t * 256;
      int r = idx >> 5, d4 = idx & 31;
      float4 v = make_float4(0.f, 0.f, 0.f, 0.f);
      if (r < Rn) v = *reinterpret_cast<const float4*>(gimg + r * Dn + base + d4 * 4);
      *reinterpret_cast<float4*>(&simg[r * IST + d4 * 4]) = v;
    }
    #pragma unroll
    for (int t = 0; t < 4; ++t) {           // 32 rows * 32 float4
      int idx = tid + t * 256;
      int l = idx >> 5, d4 = idx & 31;
      float4 v = *reinterpret_cast<const float4*>(gcap + l * Dn + base + d4 * 4);
      *reinterpret_cast<float4*>(&scap[l * CST + d4 * 4]) = v;
    }
  };

  // ---------------- phase 1: S[r][l] = img_i[r,:] . cap_c[l,:] ----------------
  const int dp = tid >> 6;        // 0..3  (D sub-window of 32 within chunk)
  const int tile = tid & 63;
  const int rt = tile >> 3;       // r = rt + 8j, j=0..4
  const int lt = tile & 7;        // l = lt + 8k, k=0..3
  const int dbase = dp * 32;

  float acc[5][4];
  #pragma unroll
  for (int j = 0; j < 5; ++j)
    #pragma unroll
    for (int k = 0; k < 4; ++k) acc[j][k] = 0.f;

  for (int ch = 0; ch < NCH; ++ch) {
    stage(ch);
    __syncthreads();
    #pragma unroll
    for (int s = 0; s < 8; ++s) {
      const int d = dbase + s * 4;
      float4 a[5], b[4];
      #pragma unroll
      for (int j = 0; j < 5; ++j)
        a[j] = *reinterpret_cast<const float4*>(&simg[(rt + 8 * j) * IST + d]);
      #pragma unroll
      for (int k = 0; k < 4; ++k)
        b[k] = *reinterpret_cast<const float4*>(&scap[(lt + 8 * k) * CST + d]);
      #pragma unroll
      for (int j = 0; j < 5; ++j)
        #pragma unroll
        for (int k = 0; k < 4; ++k)
          acc[j][k] += dot4(a[j], b[k]);
    }
    __syncthreads();
  }

  #pragma unroll
  for (int j = 0; j < 5; ++j)
    #pragma unroll
    for (int k = 0; k < 4; ++k)
      spart[dp * (Rp * Ln) + (rt + 8 * j) * Ln + (lt + 8 * k)] = acc[j][k];
  __syncthreads();

  // ---------------- phase 2: leaky + mask + row-l2norm + softmax over r -------
  #pragma unroll
  for (int t = 0; t < 5; ++t) {
    int idx = tid + t * 256;               // 0..1279 over [r<40][l<32]
    int l = idx & 31;
    float s = spart[idx] + spart[1280 + idx] + spart[2560 + idx] + spart[3840 + idx];
    s = s > 0.f ? s : SLOPE * s;
    if (l >= len) s = 0.f;
    sS[idx] = s;
    spart[idx] = s * s;                    // reuse slice 0 as squares
  }
  __syncthreads();

  if (tid < Rn) {
    float a2 = 0.f;
    #pragma unroll
    for (int l = 0; l < Ln; ++l) {
      int lp = (l + tid) & 31;             // skew to dodge bank conflicts
      a2 += spart[tid * Ln + lp];
    }
    srown[tid] = sqrtf(a2) + EPSf;
  }
  __syncthreads();

  if (tid < Ln) {
    const int l = tid;
    float z[Rn];
    float m = -1e30f;
    #pragma unroll
    for (int r = 0; r < Rn; ++r) {
      z[r] = LSM * sS[r * Ln + l] / srown[r];
      m = fmaxf(m, z[r]);
    }
    float sum = 0.f;
    #pragma unroll
    for (int r = 0; r < Rn; ++r) {
      float e = expf(z[r] - m);
      sS[r * Ln + l] = e;
      sum += e;
    }
    float inv = 1.f / sum;
    #pragma unroll
    for (int r = 0; r < Rn; ++r) sS[r * Ln + l] *= inv;   // P[r][l]
  }
  __syncthreads();

  // ---------------- phase 4/5: wctx + cosine, chunked over D ------------------
  const int dg = tid & 15;        // d = 4*dg + 64*dd (+0..3), dd=0..1
  const int lo = tid >> 4;        // l0 = lo, l1 = lo+16
  const int l0 = lo, l1 = lo + 16;

  float pr0[Rn], pr1[Rn];
  #pragma unroll
  for (int r = 0; r < Rn; ++r) {
    pr0[r] = sS[r * Ln + l0];
    pr1[r] = sS[r * Ln + l1];
  }

  float num0 = 0.f, num1 = 0.f, wn0 = 0.f, wn1 = 0.f, cn0 = 0.f, cn1 = 0.f;

  for (int ch = 0; ch < NCH; ++ch) {
    __syncthreads();               // previous chunk fully consumed
    stage(ch);
    __syncthreads();

    float4 w00 = make_float4(0,0,0,0), w01 = make_float4(0,0,0,0);
    float4 w10 = make_float4(0,0,0,0), w11 = make_float4(0,0,0,0);
    #pragma unroll
    for (int r = 0; r < Rn; ++r) {
      float4 im0 = *reinterpret_cast<const float4*>(&simg[r * IST + 4 * dg]);
      float4 im1 = *reinterpret_cast<const float4*>(&simg[r * IST + 4 * dg + 64]);
      float p0 = pr0[r], p1 = pr1[r];
      w00.x = fmaf(p0, im0.x, w00.x); w00.y = fmaf(p0, im0.y, w00.y);
      w00.z = fmaf(p0, im0.z, w00.z); w00.w = fmaf(p0, im0.w, w00.w);
      w01.x = fmaf(p0, im1.x, w01.x); w01.y = fmaf(p0, im1.y, w01.y);
      w01.z = fmaf(p0, im1.z, w01.z); w01.w = fmaf(p0, im1.w, w01.w);
      w10.x = fmaf(p1, im0.x, w10.x); w10.y = fmaf(p1, im0.y, w10.y);
      w10.z = fmaf(p1, im0.z, w10.z); w10.w = fmaf(p1, im0.w, w10.w);
      w11.x = fmaf(p1, im1.x, w11.x); w11.y = fmaf(p1, im1.y, w11.y);
      w11.z = fmaf(p1, im1.z, w11.z); w11.w = fmaf(p1, im1.w, w11.w);
    }
    float4 ca0 = *reinterpret_cast<const float4*>(&scap[l0 * CST + 4 * dg]);
    float4 ca1 = *reinterpret_cast<const float4*>(&scap[l0 * CST + 4 * dg + 64]);
    float4 cb0 = *reinterpret_cast<const float4*>(&scap[l1 * CST + 4 * dg]);
    float4 cb1 = *reinterpret_cast<const float4*>(&scap[l1 * CST + 4 * dg + 64]);
    num0 += dot4(ca0, w00) + dot4(ca1, w01);
    num1 += dot4(cb0, w10) + dot4(cb1, w11);
    wn0  += dot4(w00, w00) + dot4(w01, w01);
    wn1  += dot4(w10, w10) + dot4(w11, w11);
    cn0  += dot4(ca0, ca0) + dot4(ca1, ca1);
    cn1  += dot4(cb0, cb0) + dot4(cb1, cb1);
  }

  // reduce across the 16 dg lanes (low 4 bits of lane id)
  #pragma unroll
  for (int m = 1; m < 16; m <<= 1) {
    num0 += __shfl_xor(num0, m, 64); num1 += __shfl_xor(num1, m, 64);
    wn0  += __shfl_xor(wn0,  m, 64); wn1  += __shfl_xor(wn1,  m, 64);
    cn0  += __shfl_xor(cn0,  m, 64); cn1  += __shfl_xor(cn1,  m, 64);
  }
  if (dg == 0) {
    float d0 = fmaxf(sqrtf(cn0), EPSf) * fmaxf(sqrtf(wn0), EPSf);
    float d1 = fmaxf(sqrtf(cn1), EPSf) * fmaxf(sqrtf(wn1), EPSf);
    srs[l0] = num0 / d0;
    srs[l1] = num1 / d1;
  }
  __syncthreads();

  // ---------------- phase 6: masked LSE over l --------------------------------
  if (tid < Ln) {
    float sc = (tid < len) ? srs[tid] * LLSE : -INFINITY;
    float m = sc;
    #pragma unroll
    for (int k = 1; k < 32; k <<= 1) m = fmaxf(m, __shfl_xor(m, k, 64));
    float e = expf(sc - m);
    #pragma unroll
    for (int k = 1; k < 32; k <<= 1) e += __shfl_xor(e, k, 64);
    if (tid == 0) out[i * Cn + c] = (m + logf(e)) / LLSE;
  }
}

extern "C" void kernel_launch(void* const* d_in, const int* in_sizes, int n_in,
                              void* d_out, int out_size, void* d_ws, size_t ws_size,
                              hipStream_t stream) {
  const float* images   = (const float*)d_in[0];
  const float* captions = (const float*)d_in[1];
  const int*   cap_lens = (const int*)d_in[2];
  float* out = (float*)d_out;
  hipLaunchKernelGGL(scan_t2i, dim3(In * Cn), dim3(256), 0, stream,
                     images, captions, cap_lens, out);
}